// Round 3
// baseline (14214.644 us; speedup 1.0000x reference)
//
#include <hip/hip_runtime.h>

typedef _Float16 f16;
typedef _Float16 f16x2 __attribute__((ext_vector_type(2)));
typedef _Float16 f16x8 __attribute__((ext_vector_type(8)));
typedef float f32x4 __attribute__((ext_vector_type(4)));
typedef unsigned int uint32;

#define T_STEPS 256
#define I_DIM   512
#define H_DIM   512
#define TI      (T_STEPS * I_DIM)
#define MATSZ   262144
#define ROWS    16
#define COLS    64
#define PADC    520
#define NBLK    256

// d_ws byte layout
#define WF_BYTES  (3 * MATSZ * 2)                 // packed fp16 weights, 1.5 MB
#define HX_OFF    WF_BYTES
#define HX_BYTES  (2 * NBLK * ROWS * COLS * 4)    // h exchange, f32, parity dbuf: 2 MB
#define RHX_OFF   (HX_OFF + HX_BYTES)
#define RHX_BYTES (2 * NBLK * (ROWS/2) * COLS * 4) // r*h exchange, packed f16 pairs: 1 MB
#define FLAG_OFF  (RHX_OFF + RHX_BYTES)
#define FLAG_INTS (NBLK * 2 * 16)                  // 16-int (64B) stride per flag

#define SCOPE_AGENT __HIP_MEMORY_SCOPE_AGENT

// Pack w_hr|w_hz|w_hh into per-lane MFMA B-fragment order, fp16 (validated R1/R2).
// wf[mat][nt(32)][kk(16)][lane(64)][j(8)]; element = W[k][n],
// k = kk*32 + (lane>>4)*8 + j, n = nt*16 + (lane&15).
__global__ __launch_bounds__(256) void prep_weights(
    const float* __restrict__ w_hr, const float* __restrict__ w_hz,
    const float* __restrict__ w_hh, f16* __restrict__ wf)
{
    int idx = blockIdx.x * 256 + threadIdx.x;
    int mat = idx >> 18;
    int r   = idx & (MATSZ - 1);
    int nt  = r >> 13;
    int r1  = r & 8191;
    int kk  = r1 >> 9;
    int r2  = r1 & 511;
    int l   = r2 >> 3;
    int j   = r2 & 7;
    int k = kk * 32 + ((l >> 4) << 3) + j;
    int n = (nt << 4) + (l & 15);
    const float* W = (mat == 0) ? w_hr : (mat == 1) ? w_hz : w_hh;
    wf[idx] = (f16)W[k * H_DIM + n];
}

__global__ __launch_bounds__(256) void init_flags(int* flags)
{
    for (int i = threadIdx.x; i < FLAG_INTS; i += 256) flags[i] = 0;
}

__device__ inline void spin_ge(int* f, int tgt)
{
    long guard = 0;
    while (__hip_atomic_load(f, __ATOMIC_ACQUIRE, SCOPE_AGENT) < tgt) {
        __builtin_amdgcn_s_sleep(8);
        if (++guard > 500000) break;   // hang guard: converts deadlock -> wrong answer
    }
}

// 256 blocks x 256 threads (4 waves, 1 wave/SIMD, all 256 CUs).
// Block (rg,cg): rows [16rg,16rg+16), cols [64cg,64cg+64). Wave nt owns cols
// [64cg+16nt, +16). Recurrent weights live in 192 VGPRs/wave, loaded once.
// Per-step cross-block exchange of h (f32) and r*h (f16 pairs) through the
// coherent point (AGENT atomics) with release-flag / acquire-spin sync.
__global__ __launch_bounds__(256, 1) void grud_main(
    const float* __restrict__ data, const float* __restrict__ state,
    const float* __restrict__ w_dg_x, const float* __restrict__ w_dg_h,
    const float* __restrict__ w_xr, const float* __restrict__ w_mr,
    const float* __restrict__ w_xz, const float* __restrict__ w_mz,
    const float* __restrict__ w_xh, const float* __restrict__ w_mh,
    const float* __restrict__ b_dg_x, const float* __restrict__ b_dg_h,
    const float* __restrict__ b_r, const float* __restrict__ b_z,
    const float* __restrict__ b_h,
    char* __restrict__ ws, float* __restrict__ out)
{
    const f16*   wf   = (const f16*)ws;
    float*       hxf  = (float*)(ws + HX_OFF);
    uint32*      rhx  = (uint32*)(ws + RHX_OFF);
    int*         flags= (int*)(ws + FLAG_OFF);

    __shared__ f16   a_l[ROWS][PADC];        // A-tile: hdec (phase A) then r*h (phase B)
    __shared__ float hdecf[ROWS][COLS + 4];  // own-col decayed h, f32
    __shared__ float wdh_l[H_DIM];
    __shared__ float wcol[6][COLS];          // xr,mr,xz,mz,xh,mh (own cols)
    __shared__ float brl[ROWS][COLS + 4], bzl[ROWS][COLS + 4], bhl[ROWS][COLS + 4];
    __shared__ float dvl[ROWS], ximpl[ROWS], mvl[ROWS];
    __shared__ float wdx_l[ROWS], bdx_l[ROWS];

    const int tid = threadIdx.x;
    const int wv  = tid >> 6;            // wave = nt (0..3)
    const int l   = tid & 63;
    const int lhi = l >> 4;
    const int llo = l & 15;
    const int rg  = blockIdx.x >> 3;
    const int cg  = blockIdx.x & 7;
    const int rowbase = rg * ROWS;
    const int s_own   = blockIdx.x;      // slice id = rg*8+cg
    int* flag_h_own  = flags + (s_own * 2 + 0) * 16;
    int* flag_rh_own = flags + (s_own * 2 + 1) * 16;

    // ---- weights into registers (once) ----
    f16x8 wr[16], wz[16], wh[16];
    {
        const f16* wfb = wf + (size_t)(cg * 4 + wv) * 8192;
#pragma unroll
        for (int kk = 0; kk < 16; ++kk) {
            wr[kk] = *(const f16x8*)(wfb + (kk * 64 + l) * 8);
            wz[kk] = *(const f16x8*)(wfb + MATSZ + (kk * 64 + l) * 8);
            wh[kk] = *(const f16x8*)(wfb + 2 * MATSZ + (kk * 64 + l) * 8);
        }
    }

    // ---- t-invariant LDS staging ----
    for (int idx = tid; idx < H_DIM; idx += 256) wdh_l[idx] = w_dg_h[idx];
    for (int idx = tid; idx < 6 * COLS; idx += 256) {
        int mat = idx >> 6, c = idx & 63;
        const float* src = (mat == 0) ? w_xr : (mat == 1) ? w_mr : (mat == 2) ? w_xz
                          : (mat == 3) ? w_mz : (mat == 4) ? w_xh : w_mh;
        wcol[mat][c] = src[cg * 64 + c];
    }
    for (int idx = tid; idx < 3 * ROWS * COLS; idx += 256) {
        int which = idx >> 10, r = (idx >> 6) & 15, c = idx & 63;
        const float* src = (which == 0) ? b_r : (which == 1) ? b_z : b_h;
        float v = src[(size_t)(rowbase + r) * H_DIM + cg * 64 + c];
        if (which == 0) brl[r][c] = v; else if (which == 1) bzl[r][c] = v; else bhl[r][c] = v;
    }
    if (tid < ROWS) {
        wdx_l[tid] = w_dg_x[rowbase + tid];
        bdx_l[tid] = b_dg_x[rowbase + tid];
    }
    __syncthreads();

    const int di = tid & 15;   // decay-map row
    const int dq = tid >> 4;   // decay-map col-group (32 k each)

    float zsave[4];

    for (int t = 0; t < T_STEPS; ++t) {
        // ---- P1: flag set + spin (thread0); stage scalars (threads 16..31) ----
        if (tid == 0 && t > 0) {
            __threadfence();
            __hip_atomic_store(flag_h_own, t, __ATOMIC_RELEASE, SCOPE_AGENT);
            for (int p = 1; p < 8; ++p) {
                int cgp = (cg + p) & 7;
                spin_ge(flags + ((rg * 8 + cgp) * 2 + 0) * 16, t);
            }
        }
        if (tid >= 16 && tid < 32) {
            int i2 = tid - 16;
            int gi = rowbase + i2;
            float dd = data[2 * TI + t * I_DIM + gi];
            float mm = data[1 * TI + t * I_DIM + gi];
            float xx = data[0 * TI + t * I_DIM + gi];
            float xp = data[3 * TI + t * I_DIM + gi];
            float gx = __expf(-fmaxf(wdx_l[i2] * dd + bdx_l[i2], 0.0f));
            dvl[i2] = dd; mvl[i2] = mm;
            ximpl[i2] = mm * xx + (1.0f - mm) * gx * xp;
        }
        __syncthreads();   // P2

        // ---- P3: read full h, decay, stage A-tile ----
        {
            float dd = dvl[di];
#pragma unroll
            for (int half = 0; half < 2; ++half) {
                int k0 = dq * 32 + half * 16;
                int cgp = k0 >> 6, nb = k0 & 63;
                float hv[16];
                if (t == 0) {
                    const float* sp = state + (size_t)(rowbase + di) * H_DIM + k0;
#pragma unroll
                    for (int j = 0; j < 16; ++j) hv[j] = sp[j];
                } else {
                    float* hp = hxf + ((size_t)(t & 1) * NBLK + rg * 8 + cgp) * 1024 + di * 64 + nb;
#pragma unroll
                    for (int j = 0; j < 16; ++j)
                        hv[j] = __hip_atomic_load(hp + j, __ATOMIC_RELAXED, SCOPE_AGENT);
                }
                const float* bp = b_dg_h + (size_t)(rowbase + di) * H_DIM + k0;
                f16 hd[16];
                bool own = (cgp == cg);
#pragma unroll
                for (int j = 0; j < 16; ++j) {
                    float g = __expf(-fmaxf(dd * wdh_l[k0 + j] + bp[j], 0.0f));
                    float hdv = g * hv[j];
                    hd[j] = (f16)hdv;
                    if (own) hdecf[di][nb + j] = hdv;
                }
                f16x8 v0, v1;
#pragma unroll
                for (int j = 0; j < 8; ++j) { v0[j] = hd[j]; v1[j] = hd[8 + j]; }
                *(f16x8*)&a_l[di][k0] = v0;
                *(f16x8*)&a_l[di][k0 + 8] = v1;
            }
        }
        __syncthreads();   // P4 boundary (A-tile ready)

        // ---- Phase A: r,z GEMMs (B-operand from registers) ----
        f32x4 ar = {0.f, 0.f, 0.f, 0.f}, az = {0.f, 0.f, 0.f, 0.f};
#pragma unroll
        for (int kk = 0; kk < 16; ++kk) {
            f16x8 a = *(const f16x8*)&a_l[llo][kk * 32 + lhi * 8];
            ar = __builtin_amdgcn_mfma_f32_16x16x32_f16(a, wr[kk], ar, 0, 0, 0);
            az = __builtin_amdgcn_mfma_f32_16x16x32_f16(a, wz[kk], az, 0, 0, 0);
        }
        // epilogue A: r,z gates; export r*h slice
        {
            const int n = (wv << 4) + llo;
            uint32* rslice = rhx + ((size_t)(t & 1) * NBLK + s_own) * 512;
            float rh[4];
#pragma unroll
            for (int reg = 0; reg < 4; ++reg) {
                int i = 4 * lhi + reg;
                float sr = ar[reg] + ximpl[i] * wcol[0][n] + mvl[i] * wcol[1][n] + brl[i][n];
                float rr = 1.0f / (1.0f + __expf(-sr));
                float sz = az[reg] + ximpl[i] * wcol[2][n] + mvl[i] * wcol[3][n] + bzl[i][n];
                zsave[reg] = 1.0f / (1.0f + __expf(-sz));
                rh[reg] = rr * hdecf[i][n];
            }
#pragma unroll
            for (int b = 0; b < 2; ++b) {
                f16x2 p; p.x = (f16)rh[2 * b]; p.y = (f16)rh[2 * b + 1];
                __hip_atomic_store(rslice + (2 * lhi + b) * 64 + n,
                                   __builtin_bit_cast(uint32, p), __ATOMIC_RELAXED, SCOPE_AGENT);
            }
        }
        __syncthreads();   // P4: all a_l reads done, rh stores drained

        // ---- P5: rh flag + spin ----
        if (tid == 0) {
            __threadfence();
            __hip_atomic_store(flag_rh_own, t + 1, __ATOMIC_RELEASE, SCOPE_AGENT);
            for (int p = 1; p < 8; ++p) {
                int cgp = (cg + p) & 7;
                spin_ge(flags + ((rg * 8 + cgp) * 2 + 1) * 16, t + 1);
            }
        }
        __syncthreads();

        // ---- P6: gather r*h slices into A-tile ----
        {
            int cgp = tid >> 5, j = tid & 31;
            int rp = j >> 2, n0 = (j & 3) * 16;
            const uint32* src = rhx + ((size_t)(t & 1) * NBLK + rg * 8 + cgp) * 512 + rp * 64 + n0;
            f16 lo[16], hi[16];
#pragma unroll
            for (int jj = 0; jj < 16; ++jj) {
                uint32 u = __hip_atomic_load((uint32*)(src + jj), __ATOMIC_RELAXED, SCOPE_AGENT);
                f16x2 p = __builtin_bit_cast(f16x2, u);
                lo[jj] = p.x; hi[jj] = p.y;
            }
            int k0 = cgp * 64 + n0;
            f16x8 v0, v1, v2, v3;
#pragma unroll
            for (int jj = 0; jj < 8; ++jj) {
                v0[jj] = lo[jj]; v1[jj] = lo[8 + jj];
                v2[jj] = hi[jj]; v3[jj] = hi[8 + jj];
            }
            *(f16x8*)&a_l[2 * rp][k0]     = v0;
            *(f16x8*)&a_l[2 * rp][k0 + 8] = v1;
            *(f16x8*)&a_l[2 * rp + 1][k0]     = v2;
            *(f16x8*)&a_l[2 * rp + 1][k0 + 8] = v3;
        }
        __syncthreads();

        // ---- Phase B: h_tilde GEMM ----
        f32x4 ah = {0.f, 0.f, 0.f, 0.f};
#pragma unroll
        for (int kk = 0; kk < 16; ++kk) {
            f16x8 a = *(const f16x8*)&a_l[llo][kk * 32 + lhi * 8];
            ah = __builtin_amdgcn_mfma_f32_16x16x32_f16(a, wh[kk], ah, 0, 0, 0);
        }
        // epilogue B: h_new, output store, h export
        {
            const int n = (wv << 4) + llo;
            const int gcol = cg * 64 + n;
            float* hslice = hxf + ((size_t)((t + 1) & 1) * NBLK + s_own) * 1024;
#pragma unroll
            for (int reg = 0; reg < 4; ++reg) {
                int i = 4 * lhi + reg;
                int gi = rowbase + i;
                float sh = ah[reg] + ximpl[i] * wcol[4][n] + mvl[i] * wcol[5][n] + bhl[i][n];
                float e  = __expf(2.0f * sh);
                float th = 1.0f - 2.0f / (e + 1.0f);
                float hd = hdecf[i][n];
                float hn = (1.0f - zsave[reg]) * hd + zsave[reg] * th;
                __builtin_nontemporal_store(hn, &out[((size_t)t * I_DIM + gi) * H_DIM + gcol]);
                __hip_atomic_store(hslice + i * 64 + n, hn, __ATOMIC_RELAXED, SCOPE_AGENT);
            }
        }
        __syncthreads();   // Pend: h stores drained before next-step flag
    }
}

extern "C" void kernel_launch(void* const* d_in, const int* in_sizes, int n_in,
                              void* d_out, int out_size, void* d_ws, size_t ws_size,
                              hipStream_t stream) {
    const float* data   = (const float*)d_in[0];
    const float* state  = (const float*)d_in[1];
    const float* w_dg_x = (const float*)d_in[2];
    const float* w_dg_h = (const float*)d_in[3];
    const float* w_xr   = (const float*)d_in[4];
    const float* w_hr   = (const float*)d_in[5];
    const float* w_mr   = (const float*)d_in[6];
    const float* w_xz   = (const float*)d_in[7];
    const float* w_hz   = (const float*)d_in[8];
    const float* w_mz   = (const float*)d_in[9];
    const float* w_xh   = (const float*)d_in[10];
    const float* w_hh   = (const float*)d_in[11];
    const float* w_mh   = (const float*)d_in[12];
    const float* b_dg_x = (const float*)d_in[13];
    const float* b_dg_h = (const float*)d_in[14];
    const float* b_r    = (const float*)d_in[15];
    const float* b_z    = (const float*)d_in[16];
    const float* b_h    = (const float*)d_in[17];
    char* ws = (char*)d_ws;
    float* out = (float*)d_out;

    prep_weights<<<3072, 256, 0, stream>>>(w_hr, w_hz, w_hh, (f16*)ws);
    init_flags<<<1, 256, 0, stream>>>((int*)(ws + FLAG_OFF));
    grud_main<<<NBLK, 256, 0, stream>>>(data, state, w_dg_x, w_dg_h,
        w_xr, w_mr, w_xz, w_mz, w_xh, w_mh,
        b_dg_x, b_dg_h, b_r, b_z, b_h, ws, out);
}